// Round 5
// baseline (398.843 us; speedup 1.0000x reference)
//
#include <hip/hip_runtime.h>
#include <math.h>

#define EPSF   1e-15f
#define CLIP1  0.99999988f   /* fp32(1 - 1e-7) */
#define MAXNRM 0.99999f      /* (1 - 1e-5)/sqrt(c), c = 1 */

typedef __bf16 bf16x8 __attribute__((ext_vector_type(8)));
typedef float floatx4 __attribute__((ext_vector_type(4)));

// ---------------------------------------------------------------- utilities
__device__ __forceinline__ float wred(float x) {
#pragma unroll
  for (int o = 32; o; o >>= 1) x += __shfl_xor(x, o);
  return x;
}

__device__ __forceinline__ unsigned short f2bf(float f) {
  unsigned int u = __float_as_uint(f);
  u += 0x7fffu + ((u >> 16) & 1u);   // RNE
  return (unsigned short)(u >> 16);
}

__device__ __forceinline__ void gl_lds16(const ushort* g, ushort* l) {
  __builtin_amdgcn_global_load_lds(
      (const __attribute__((address_space(1))) void*)g,
      (__attribute__((address_space(3))) void*)l, 16, 0, 0);
}

// ---------------------------------------------------------------- Z -> fragment-ordered bf16 (+ column norms^2)
__global__ __launch_bounds__(256) void k_zpack(const float* __restrict__ Z1,
                                               const float* __restrict__ Z2,
                                               ushort* __restrict__ ZF,
                                               float* __restrict__ ZN2) {
  __shared__ float zs[32 * 256];
  int kt = blockIdx.x, mat = blockIdx.y;
  const float* Z = mat ? Z2 : Z1;
  ushort* out = ZF + (size_t)mat * 589824;
  int t = threadIdx.x;
  const float4* src = (const float4*)(Z + kt * 32 * 256);
  float4* dst4 = (float4*)zs;
#pragma unroll
  for (int i = 0; i < 8; ++i) dst4[t + i * 256] = src[t + i * 256];
  __syncthreads();
  {
    float acc = 0.f;
#pragma unroll 8
    for (int k = 0; k < 32; ++k) {
      float z = zs[k * 256 + t];
      acc = fmaf(z, z, acc);
    }
    atomicAdd(&ZN2[mat * 256 + t], acc);
  }
  int l = t & 63, sub = t >> 6;
  for (int i = 0; i < 4; ++i) {
    int combo = sub * 4 + i;                 // ctg 0..15
    int col = combo * 16 + (l & 15);
    int krow = (l >> 4) * 8;
    unsigned int pk[4];
#pragma unroll
    for (int j = 0; j < 4; ++j) {
      unsigned int lo = f2bf(zs[(krow + 2 * j) * 256 + col]);
      unsigned int hi = f2bf(zs[(krow + 2 * j + 1) * 256 + col]);
      pk[j] = lo | (hi << 16);
    }
    uint4* o = (uint4*)(out + ((size_t)(kt * 16 + combo)) * 512 + l * 8);
    *o = make_uint4(pk[0], pk[1], pk[2], pk[3]);
  }
}

// ---------------------------------------------------------------- x[B,C,H,W] -> xl fp32, Vp bf16(padded), nv2
__global__ __launch_bounds__(256) void k_pre1(const float* __restrict__ X,
                                              float* __restrict__ XL,
                                              ushort* __restrict__ Vp,
                                              float* __restrict__ NV2,
                                              float scale) {
  __shared__ float tile[256 * 33];
  __shared__ float facs[32];
  const int b = blockIdx.x >> 5, h = blockIdx.x & 31;
  const int t = threadIdx.x;
  for (int c0 = 0; c0 < 256; c0 += 8) {
    int c = c0 + (t >> 5), w = t & 31;
    tile[c * 33 + w] = X[((b * 256 + c) * 32 + h) * 32 + w];
  }
  __syncthreads();
  {
    int w = t >> 3, s = t & 7;
    float n2 = 0.f;
#pragma unroll 8
    for (int i = 0; i < 32; ++i) {
      float xv = tile[(s + 8 * i) * 33 + w];
      n2 = fmaf(xv, xv, n2);
    }
    n2 += __shfl_xor(n2, 1); n2 += __shfl_xor(n2, 2); n2 += __shfl_xor(n2, 4);
    float n = sqrtf(fmaxf(n2, EPSF));
    float fac = atanhf(fminf(n, CLIP1)) / n * scale;
    if (s == 0) {
      facs[w] = fac;
      NV2[blockIdx.x * 32 + w] = fac * fac * n2;
    }
  }
  __syncthreads();
  const int g = t & 63;
  const int pix0 = blockIdx.x * 32;
#pragma unroll
  for (int it = 0; it < 8; ++it) {
    int p = (t >> 6) + it * 4;
    float f = facs[p];
    float4 val;
    val.x = tile[(g * 4 + 0) * 33 + p];
    val.y = tile[(g * 4 + 1) * 33 + p];
    val.z = tile[(g * 4 + 2) * 33 + p];
    val.w = tile[(g * 4 + 3) * 33 + p];
    *(float4*)(XL + (size_t)(pix0 + p) * 256 + g * 4) = val;
    ushort4 vb;
    vb.x = f2bf(val.x * f); vb.y = f2bf(val.y * f);
    vb.z = f2bf(val.z * f); vb.w = f2bf(val.w * f);
    *(ushort4*)(Vp + ((size_t)((b * 34 + h + 1) * 34 + (p + 1))) * 256 + g * 4) = vb;
  }
}

// ---------------------------------------------------------------- 3x3 box sum of nv2
__global__ __launch_bounds__(256) void k_boxsum(const float* __restrict__ NV2,
                                                float* __restrict__ P2) {
  int pix = blockIdx.x * 256 + threadIdx.x;
  int hw = pix & 1023, hh = hw >> 5, ww = hw & 31, base = pix & ~1023;
  float s = 0.f;
#pragma unroll
  for (int di = -1; di <= 1; ++di)
#pragma unroll
    for (int dj = -1; dj <= 1; ++dj) {
      int sh = hh + di, sw = ww + dj;
      if ((unsigned)sh < 32u && (unsigned)sw < 32u) s += NV2[base + sh * 32 + sw];
    }
  P2[pix] = s;
}

// ---------------------------------------------------------------- MFMA implicit-GEMM conv
// tile 128 rows x 64 cols, BK=64, XCD-swizzled 1D grid of 512
__global__ __launch_bounds__(256) void k_gemm_mfma(const ushort* __restrict__ Vp,
                                                   const ushort* __restrict__ ZF,
                                                   float* __restrict__ S) {
  __shared__ ushort lds[24576];  // 2 bufs x (16KB A + 8KB B)
  const int t = threadIdx.x;
  const int w = t >> 6, l = t & 63;
  const int l15 = l & 15, l16 = l >> 4;
  // XCD swizzle: 4 col-splits of one row-strip land on the same XCD (g % 8)
  const int g = blockIdx.x;
  const int xcd = g & 7, gi = g >> 3;
  const int rowb = (gi >> 2) * 8 + xcd;   // 0..127
  const int colb = gi & 3;                // 0..3
  const int col0 = colb * 64, row0 = rowb * 128;
  const int cb4 = colb * 4;

  int abase[2];
#pragma unroll
  for (int i = 0; i < 2; ++i) {
    int r = row0 + (w + i * 4) * 16 + l15;
    int b = r >> 10, h = (r >> 5) & 31, wc = r & 31;
    abase[i] = ((b * 34 + h + 1) * 34 + (wc + 1)) * 256 + l16 * 8;
  }

  floatx4 acc[2][4];
#pragma unroll
  for (int i = 0; i < 2; ++i)
#pragma unroll
    for (int j = 0; j < 4; ++j) acc[i][j] = (floatx4){0.f, 0.f, 0.f, 0.f};

  auto stage = [&](int buf, int kt) {
    int tap = kt >> 2, cin0 = (kt & 3) << 6;
    int koff = ((tap / 3 - 1) * 34 + (tap % 3 - 1)) * 256 + cin0;
    ushort* Ad = lds + buf * 12288;
    ushort* Bd = Ad + 8192;
#pragma unroll
    for (int ii = 0; ii < 4; ++ii) {
      int bi = w + ii * 4;
      int s = bi >> 3;
      gl_lds16(Vp + abase[ii & 1] + koff + s * 32, Ad + bi * 512);
    }
#pragma unroll
    for (int ii = 0; ii < 2; ++ii) {
      int bj = w + ii * 4;
      int s = bj >> 2, ct = bj & 3;
      gl_lds16(ZF + ((size_t)((kt * 2 + s) * 16 + cb4 + ct)) * 512 + l * 8,
               Bd + bj * 512);
    }
  };

  auto compute = [&](int buf) {
    const ushort* Ab = lds + buf * 12288;
    const ushort* Bb = Ab + 8192;
    bf16x8 a[2][2], b[2][4];
#pragma unroll
    for (int s = 0; s < 2; ++s) {
#pragma unroll
      for (int i = 0; i < 2; ++i)
        a[s][i] = *(const bf16x8*)(Ab + (s * 8 + w * 2 + i) * 512 + l * 8);
#pragma unroll
      for (int j = 0; j < 4; ++j)
        b[s][j] = *(const bf16x8*)(Bb + (s * 4 + j) * 512 + l * 8);
    }
#pragma unroll
    for (int s = 0; s < 2; ++s)
#pragma unroll
      for (int i = 0; i < 2; ++i)
#pragma unroll
        for (int j = 0; j < 4; ++j)
          acc[i][j] = __builtin_amdgcn_mfma_f32_16x16x32_bf16(a[s][i], b[s][j],
                                                              acc[i][j], 0, 0, 0);
  };

  stage(0, 0);
  for (int kt = 0; kt < 36; ++kt) {
    __syncthreads();
    if (kt + 1 < 36) stage((kt + 1) & 1, kt + 1);
    compute(kt & 1);
  }

#pragma unroll
  for (int i = 0; i < 2; ++i) {
    int r = row0 + w * 32 + i * 16 + l16 * 4;
#pragma unroll
    for (int j = 0; j < 4; ++j) {
      int c = col0 + j * 16 + l15;
#pragma unroll
      for (int reg = 0; reg < 4; ++reg)
        S[(size_t)(r + reg) * 256 + c] = acc[i][j][reg];
    }
  }
}

// ---------------------------------------------------------------- Poincare-FC epilogue + BN reduction 1 (fused)
// 256 blocks x 64 pixels; writes h + per-block NUM/DEN partials
__global__ __launch_bounds__(256) void k_fcepi_red(const float* __restrict__ S,
                                                   const float* __restrict__ P2,
                                                   const float* __restrict__ ZN2,
                                                   float* __restrict__ H,
                                                   float* __restrict__ PNUM,
                                                   float* __restrict__ PDEN) {
  __shared__ float snum[256];
  __shared__ float sden;
  int t = threadIdx.x, lane = t & 63, wv = t >> 6;
  snum[t] = 0.f;
  if (t == 0) sden = 0.f;
  __syncthreads();
  float4 z2 = ((const float4*)ZN2)[lane];
  float zn[4] = {sqrtf(fmaxf(z2.x, EPSF)), sqrtf(fmaxf(z2.y, EPSF)),
                 sqrtf(fmaxf(z2.z, EPSF)), sqrtf(fmaxf(z2.w, EPSF))};
  float acc[4] = {0.f, 0.f, 0.f, 0.f};
  float accd = 0.f;
  for (int it = 0; it < 16; ++it) {
    int pix = blockIdx.x * 64 + it * 4 + wv;
    float4 sv = ((const float4*)S)[pix * 64 + lane];
    float p2 = P2[pix];
    float np = sqrtf(fmaxf(p2, EPSF));
    float un = tanhf(np);
    float f = un / np;
    if (un > MAXNRM) f *= MAXNRM / un;
    float u2 = f * f * p2;
    float lamu = 2.f / fmaxf(1.f - u2, EPSF);
    float lf = lamu * f;
    float sval[4] = {sv.x, sv.y, sv.z, sv.w};
    float y[4];
#pragma unroll
    for (int k = 0; k < 4; ++k) {
      float d = 2.f * zn[k] * asinhf(lf * sval[k] / zn[k]);
      y[k] = sinhf(d);
    }
    float y2 = wred(y[0] * y[0] + y[1] * y[1] + y[2] * y[2] + y[3] * y[3]);
    float inv = 1.f / (1.f + sqrtf(1.f + y2));
    float h[4] = {y[0] * inv, y[1] * inv, y[2] * inv, y[3] * inv};
    ((float4*)H)[pix * 64 + lane] = make_float4(h[0], h[1], h[2], h[3]);
    float hn2 = y2 * inv * inv;
    float lam = 2.f / fmaxf(1.f - hn2, EPSF);
#pragma unroll
    for (int k = 0; k < 4; ++k) acc[k] = fmaf(lam, h[k], acc[k]);
    if (lane == 0) accd += lam - 1.f;
  }
  atomicAdd(&snum[lane * 4 + 0], acc[0]);
  atomicAdd(&snum[lane * 4 + 1], acc[1]);
  atomicAdd(&snum[lane * 4 + 2], acc[2]);
  atomicAdd(&snum[lane * 4 + 3], acc[3]);
  if (lane == 0) atomicAdd(&sden, accd);
  __syncthreads();
  PNUM[t * 256 + blockIdx.x] = snum[t];
  if (t == 0) PDEN[blockIdx.x] = sden;
}

// ---------------------------------------------------------------- BN midpoint + scalars (reduces partials)
__global__ __launch_bounds__(256) void k_bnmid(const float* __restrict__ PNUM,
                                               const float* __restrict__ PDEN,
                                               const float* __restrict__ BIAS,
                                               float* __restrict__ MU,
                                               float* __restrict__ SCAL) {
  __shared__ float sb[4];
  int t = threadIdx.x, lane = t & 63, wv = t >> 6;
  auto bred = [&](float v) {
    v = wred(v);
    __syncthreads();
    if (lane == 0) sb[wv] = v;
    __syncthreads();
    return sb[0] + sb[1] + sb[2] + sb[3];
  };
  float num = 0.f;
  const float4* pn = (const float4*)(PNUM + t * 256);
#pragma unroll 8
  for (int i = 0; i < 64; ++i) {
    float4 v = pn[i];
    num += (v.x + v.y) + (v.z + v.w);
  }
  float den = bred(PDEN[t]);
  float m = num / fmaxf(den, EPSF);
  float n2m = bred(m * m);
  float n = sqrtf(fmaxf(n2m, EPSF));
  float midf = tanhf(0.5f * atanhf(fminf(n, CLIP1))) / n;
  float mu = m * midf;
  MU[t] = mu;
  float bv = BIAS[t];
  float bias2 = bred(bv * bv);
  float mubias = bred(bv * mu);
  if (t == 0) {
    float mu2 = midf * midf * n2m;
    SCAL[0] = mu2;
    SCAL[1] = 2.f / fmaxf(1.f - mu2, EPSF);
    SCAL[2] = bias2;
    SCAL[3] = 2.f / fmaxf(1.f - bias2, EPSF);
    SCAL[4] = mubias;
  }
}

// ---------------------------------------------------------------- BN reduction 2 (var)
__global__ __launch_bounds__(256) void k_bnred2(const float* __restrict__ Hin,
                                                const float* __restrict__ MU,
                                                const float* __restrict__ SCAL,
                                                float* __restrict__ VAR) {
  __shared__ float sp[4];
  int t = threadIdx.x, lane = t & 63, wv = t >> 6;
  float4 muv = ((const float4*)MU)[lane];
  float mu2 = SCAL[0];
  float accd = 0.f;
  for (int it = 0; it < 32; ++it) {
    int pix = blockIdx.x * 128 + it * 4 + wv;
    float4 hv = ((const float4*)Hin)[pix * 64 + lane];
    float x2 = wred(hv.x * hv.x + hv.y * hv.y + hv.z * hv.z + hv.w * hv.w);
    float xmu = wred(hv.x * muv.x + hv.y * muv.y + hv.z * muv.z + hv.w * muv.w);
    float A = 1.f - 2.f * xmu + mu2;
    float B = 1.f - x2;
    float num2 = A * A * x2 + B * B * mu2 - 2.f * A * B * xmu;
    float den = fmaxf(1.f - 2.f * xmu + x2 * mu2, EPSF);
    float nn = sqrtf(fmaxf(num2 / (den * den), EPSF));
    float dist = 2.f * atanhf(fminf(nn, CLIP1));
    accd += dist * dist;
  }
  if (lane == 0) sp[wv] = accd;
  __syncthreads();
  if (t == 0) atomicAdd(VAR, sp[0] + sp[1] + sp[2] + sp[3]);
}

// ---------------------------------------------------------------- BN transform core (shared by both variants)
// returns post-BN point r[4] (pre-residual, pre-hrelu), plus its norm nr
template <bool CLIPR>
__device__ __forceinline__ void bn_core(const float x[4], const float mm[4],
                                        const float bs[4], float mu2, float lam_mu,
                                        float bias2, float lam_bias, float mubias,
                                        float rstd, float r[4], float& nr) {
  float x2 = wred(x[0] * x[0] + x[1] * x[1] + x[2] * x[2] + x[3] * x[3]);
  float xmu = wred(x[0] * mm[0] + x[1] * mm[1] + x[2] * mm[2] + x[3] * mm[3]);
  float P = 1.f - 2.f * xmu + x2, Q = 1.f - mu2;
  float den1i = 1.f / fmaxf(1.f - 2.f * xmu + mu2 * x2, EPSF);
  float d[4];
#pragma unroll
  for (int k = 0; k < 4; ++k) d[k] = (Q * x[k] - P * mm[k]) * den1i;
  float nd2 = wred(d[0] * d[0] + d[1] * d[1] + d[2] * d[2] + d[3] * d[3]);
  float nd = sqrtf(fmaxf(nd2, EPSF));
  float vfac = (2.f / lam_mu) * atanhf(fminf(nd, CLIP1)) / nd;
  float v[4];
#pragma unroll
  for (int k = 0; k < 4; ++k) v[k] = vfac * d[k];
  float uw = wred(bs[0] * v[0] + bs[1] * v[1] + bs[2] * v[2] + bs[3] * v[3]);
  float mv = wred(mm[0] * v[0] + mm[1] * v[1] + mm[2] * v[2] + mm[3] * v[3]);
  float vw = -mv, uv = -mubias;
  float ga = -(uw * mu2) - vw + 2.f * uv * vw;
  float gb = -(vw * bias2) + uw;
  float ddi = 1.f / fmaxf(1.f + 2.f * uv + bias2 * mu2, EPSF);
  float sgy = (lam_mu / lam_bias) * rstd;
  float u[4];
#pragma unroll
  for (int k = 0; k < 4; ++k)
    u[k] = (v[k] + 2.f * (ga * bs[k] - gb * mm[k]) * ddi) * sgy;
  float nu2 = wred(u[0] * u[0] + u[1] * u[1] + u[2] * u[2] + u[3] * u[3]);
  float bu = wred(bs[0] * u[0] + bs[1] * u[1] + bs[2] * u[2] + bs[3] * u[3]);
  float nu = sqrtf(fmaxf(nu2, EPSF));
  float sfac = tanhf(lam_bias * nu * 0.5f) / nu;
  float y2 = sfac * sfac * nu2, xy = sfac * bu;
  float P2 = 1.f + 2.f * xy + y2, Q2 = 1.f - bias2;
  float den2i = 1.f / fmaxf(1.f + 2.f * xy + bias2 * y2, EPSF);
#pragma unroll
  for (int k = 0; k < 4; ++k) r[k] = (P2 * bs[k] + Q2 * sfac * u[k]) * den2i;
  float nr2 = wred(r[0] * r[0] + r[1] * r[1] + r[2] * r[2] + r[3] * r[3]);
  nr = sqrtf(fmaxf(nr2, EPSF));
  if (CLIPR && nr > MAXNRM) {
    float sc = MAXNRM / nr;
#pragma unroll
    for (int k = 0; k < 4; ++k) r[k] *= sc;
    nr = MAXNRM;
  }
}

// ---------------------------------------------------------------- BN1 transform + hrelu + logmap0*scale -> Vp,NV2
// (logmap0(expmap0(t)) == t, so we emit the tangent directly; skips h write + preB pass)
__global__ __launch_bounds__(256) void k_bntrans_pre(const float* __restrict__ Hin,
                                                     const float* __restrict__ MU,
                                                     const float* __restrict__ SCAL,
                                                     const float* __restrict__ BIAS,
                                                     const float* __restrict__ WEIGHT,
                                                     const float* __restrict__ VAR,
                                                     ushort* __restrict__ Vp,
                                                     float* __restrict__ NV2,
                                                     float scale) {
  int pix = blockIdx.x * 4 + (threadIdx.x >> 6);
  int lane = threadIdx.x & 63;
  float4 xv4 = ((const float4*)Hin)[pix * 64 + lane];
  float4 mu4 = ((const float4*)MU)[lane];
  float4 bb4 = ((const float4*)BIAS)[lane];
  float mu2 = SCAL[0], lam_mu = SCAL[1], bias2 = SCAL[2], lam_bias = SCAL[3],
        mubias = SCAL[4];
  float var = VAR[0] * (1.f / 16384.f);
  float rstd = sqrtf(WEIGHT[0] / fmaxf(var, EPSF));
  float x[4] = {xv4.x, xv4.y, xv4.z, xv4.w};
  float mm[4] = {mu4.x, mu4.y, mu4.z, mu4.w};
  float bs[4] = {bb4.x, bb4.y, bb4.z, bb4.w};
  float r[4], nr;
  bn_core<true>(x, mm, bs, mu2, lam_mu, bias2, lam_bias, mubias, rstd, r, nr);
  // hrelu tangent: t = relu(atanh(nr)/nr * r); output v = t*scale (logmap0∘expmap0 cancels)
  float tf = atanhf(fminf(nr, CLIP1)) / nr;
  float tr[4];
#pragma unroll
  for (int k = 0; k < 4; ++k) tr[k] = fmaxf(tf * r[k], 0.f);
  float nt2 = wred(tr[0] * tr[0] + tr[1] * tr[1] + tr[2] * tr[2] + tr[3] * tr[3]);
  int b = pix >> 10, hh = (pix >> 5) & 31, ww = pix & 31;
  ushort4 vb;
  vb.x = f2bf(tr[0] * scale); vb.y = f2bf(tr[1] * scale);
  vb.z = f2bf(tr[2] * scale); vb.w = f2bf(tr[3] * scale);
  *(ushort4*)(Vp + ((size_t)((b * 34 + hh + 1) * 34 + (ww + 1))) * 256 + lane * 4) = vb;
  if (lane == 0) NV2[pix] = nt2 * scale * scale;
}

// ---------------------------------------------------------------- BN2 transform + residual + hrelu + [B,C,H,W] store
// block = one (b,h) row of 32 pixels; LDS transpose for coalesced output
__global__ __launch_bounds__(256) void k_bntrans_out(const float* __restrict__ Hin,
                                                     const float* __restrict__ MU,
                                                     const float* __restrict__ SCAL,
                                                     const float* __restrict__ BIAS,
                                                     const float* __restrict__ WEIGHT,
                                                     const float* __restrict__ VAR,
                                                     const float* __restrict__ RES,
                                                     float* __restrict__ Out) {
  __shared__ float tile[256 * 33];
  int t = threadIdx.x, lane = t & 63, wv = t >> 6;
  float4 mu4 = ((const float4*)MU)[lane];
  float4 bb4 = ((const float4*)BIAS)[lane];
  float mu2 = SCAL[0], lam_mu = SCAL[1], bias2 = SCAL[2], lam_bias = SCAL[3],
        mubias = SCAL[4];
  float var = VAR[0] * (1.f / 16384.f);
  float rstd = sqrtf(WEIGHT[0] / fmaxf(var, EPSF));
  float mm[4] = {mu4.x, mu4.y, mu4.z, mu4.w};
  float bs[4] = {bb4.x, bb4.y, bb4.z, bb4.w};
  int pix0 = blockIdx.x * 32;
  for (int it = 0; it < 8; ++it) {
    int p = it * 4 + wv;
    int pix = pix0 + p;
    float4 xv4 = ((const float4*)Hin)[pix * 64 + lane];
    float x[4] = {xv4.x, xv4.y, xv4.z, xv4.w};
    float r[4], nr;
    bn_core<true>(x, mm, bs, mu2, lam_mu, bias2, lam_bias, mubias, rstd, r, nr);
    // mobius_add(r, res)
    float h2 = nr * nr;
    float4 rs4 = ((const float4*)RES)[pix * 64 + lane];
    float rr[4] = {rs4.x, rs4.y, rs4.z, rs4.w};
    float y2r = wred(rr[0] * rr[0] + rr[1] * rr[1] + rr[2] * rr[2] + rr[3] * rr[3]);
    float xyr = wred(r[0] * rr[0] + r[1] * rr[1] + r[2] * rr[2] + r[3] * rr[3]);
    float Pm = 1.f + 2.f * xyr + y2r, Qm = 1.f - h2;
    float denmi = 1.f / fmaxf(1.f + 2.f * xyr + h2 * y2r, EPSF);
#pragma unroll
    for (int k = 0; k < 4; ++k) r[k] = (Pm * r[k] + Qm * rr[k]) * denmi;
    float nr2 = wred(r[0] * r[0] + r[1] * r[1] + r[2] * r[2] + r[3] * r[3]);
    nr = sqrtf(fmaxf(nr2, EPSF));
    // hrelu
    float tf = atanhf(fminf(nr, CLIP1)) / nr;
    float tr[4];
#pragma unroll
    for (int k = 0; k < 4; ++k) tr[k] = fmaxf(tf * r[k], 0.f);
    float nt2 = wred(tr[0] * tr[0] + tr[1] * tr[1] + tr[2] * tr[2] + tr[3] * tr[3]);
    float nt = sqrtf(fmaxf(nt2, EPSF));
    float une = tanhf(nt);
    float ef = une / nt;
    if (une > MAXNRM) ef *= MAXNRM / une;
#pragma unroll
    for (int k = 0; k < 4; ++k) tile[(lane * 4 + k) * 33 + p] = ef * tr[k];
  }
  __syncthreads();
  int b = blockIdx.x >> 5, h = blockIdx.x & 31;
  for (int c0 = 0; c0 < 256; c0 += 8) {
    int c = c0 + (t >> 5), w = t & 31;
    Out[((b * 256 + c) * 32 + h) * 32 + w] = tile[c * 33 + w];
  }
}

// ---------------------------------------------------------------- launch
extern "C" void kernel_launch(void* const* d_in, const int* in_sizes, int n_in,
                              void* d_out, int out_size, void* d_ws, size_t ws_size,
                              hipStream_t stream) {
  (void)in_sizes; (void)n_in; (void)out_size; (void)ws_size;
  const float* x  = (const float*)d_in[0];
  const float* z1 = (const float*)d_in[1];
  const float* z2 = (const float*)d_in[2];
  const float* w1 = (const float*)d_in[3];
  const float* b1 = (const float*)d_in[4];
  const float* w2 = (const float*)d_in[5];
  const float* b2 = (const float*)d_in[6];
  float* out = (float*)d_out;
  float* ws = (float*)d_ws;

  float* zn2   = ws;            // 512
  float* var   = ws + 512;      // 1
  float* mu    = ws + 768;      // 256 (16B aligned)
  float* scal  = ws + 1024;     // 8
  float* pden  = ws + 1088;     // 256
  float* pnum  = ws + 2048;     // 256*256 (16B aligned, row stride 1KB)
  float* nv2   = ws + 67584;    // 16384
  float* p2    = ws + 83968;    // 16384
  float* xl    = ws + 100352;   // 16 MB (16B aligned)
  float* h     = xl + 4194304;  // 16 MB
  float* s     = h + 4194304;   // 16 MB
  ushort* Vp   = (ushort*)(s + 4194304);  // 16*34*34*256 bf16 = 9.47 MB
  ushort* ZF   = Vp + 4734976;            // 2 x 589824 bf16

  double lb = (lgamma(1152.0) - lgamma(1152.5)) - (lgamma(128.0) - lgamma(128.5));
  float scale = (float)exp(lb);

  hipMemsetAsync(ws, 0, 768 * sizeof(float), stream);     // zn2 + var
  hipMemsetAsync(Vp, 0, (size_t)4734976 * 2, stream);     // zero padding borders
  k_zpack<<<dim3(72, 2), 256, 0, stream>>>(z1, z2, ZF, zn2);

  // ---- conv1
  k_pre1<<<512, 256, 0, stream>>>(x, xl, Vp, nv2, scale);
  k_boxsum<<<64, 256, 0, stream>>>(nv2, p2);
  k_gemm_mfma<<<512, 256, 0, stream>>>(Vp, ZF, s);
  k_fcepi_red<<<256, 256, 0, stream>>>(s, p2, zn2, h, pnum, pden);
  k_bnmid<<<1, 256, 0, stream>>>(pnum, pden, b1, mu, scal);
  k_bnred2<<<128, 256, 0, stream>>>(h, mu, scal, var);
  k_bntrans_pre<<<4096, 256, 0, stream>>>(h, mu, scal, b1, w1, var, Vp, nv2, scale);
  hipMemsetAsync(var, 0, sizeof(float), stream);          // re-zero for conv2

  // ---- conv2
  k_boxsum<<<64, 256, 0, stream>>>(nv2, p2);
  k_gemm_mfma<<<512, 256, 0, stream>>>(Vp, ZF + 589824, s);
  k_fcepi_red<<<256, 256, 0, stream>>>(s, p2, zn2 + 256, h, pnum, pden);
  k_bnmid<<<1, 256, 0, stream>>>(pnum, pden, b2, mu, scal);
  k_bnred2<<<128, 256, 0, stream>>>(h, mu, scal, var);
  k_bntrans_out<<<512, 256, 0, stream>>>(h, mu, scal, b2, w2, var, xl, out);
}

// Round 6
// 294.189 us; speedup vs baseline: 1.3557x; 1.3557x over previous
//
#include <hip/hip_runtime.h>
#include <math.h>

#define EPSF   1e-15f
#define CLIP1  0.99999988f   /* fp32(1 - 1e-7) */
#define MAXNRM 0.99999f      /* (1 - 1e-5)/sqrt(c), c = 1 */
#define LOG2E  1.44269504088896f
#define LN2    0.69314718055994f

typedef __bf16 bf16x8 __attribute__((ext_vector_type(8)));
typedef float floatx4 __attribute__((ext_vector_type(4)));

// ---------------------------------------------------------------- utilities
__device__ __forceinline__ float wred(float x) {
#pragma unroll
  for (int o = 32; o; o >>= 1) x += __shfl_xor(x, o);
  return x;
}

__device__ __forceinline__ float frcp(float x) { return __builtin_amdgcn_rcpf(x); }
__device__ __forceinline__ float flog2(float x) { return __builtin_amdgcn_logf(x); }
__device__ __forceinline__ float fexp2(float x) { return __builtin_amdgcn_exp2f(x); }

// atanh for x in [0, CLIP1]
__device__ __forceinline__ float atanh_fast(float x) {
  return 0.5f * LN2 * flog2((1.f + x) * frcp(1.f - x));
}
// tanh for x >= 0
__device__ __forceinline__ float tanh_fast(float x) {
  float q = fexp2(fminf(2.f * LOG2E * x, 126.f));
  return (q - 1.f) * frcp(q + 1.f);
}
// sinh(2*z*asinh(w)), z > 0
__device__ __forceinline__ float sinh2zasinh(float z, float w) {
  float aw = fabsf(w);
  float tt = aw + sqrtf(fmaf(aw, aw, 1.f));
  float k2 = fminf(2.f * z * flog2(tt), 126.f);
  float q = fexp2(k2);
  return copysignf(0.5f * (q - frcp(q)), w);
}

__device__ __forceinline__ unsigned short f2bf(float f) {
  unsigned int u = __float_as_uint(f);
  u += 0x7fffu + ((u >> 16) & 1u);   // RNE
  return (unsigned short)(u >> 16);
}

__device__ __forceinline__ void gl_lds16(const ushort* g, ushort* l) {
  __builtin_amdgcn_global_load_lds(
      (const __attribute__((address_space(1))) void*)g,
      (__attribute__((address_space(3))) void*)l, 16, 0, 0);
}

// ---------------------------------------------------------------- Z -> fragment-ordered bf16 (+ column norms^2)
__global__ __launch_bounds__(256) void k_zpack(const float* __restrict__ Z1,
                                               const float* __restrict__ Z2,
                                               ushort* __restrict__ ZF,
                                               float* __restrict__ ZN2) {
  __shared__ float zs[32 * 256];
  int kt = blockIdx.x, mat = blockIdx.y;
  const float* Z = mat ? Z2 : Z1;
  ushort* out = ZF + (size_t)mat * 589824;
  int t = threadIdx.x;
  const float4* src = (const float4*)(Z + kt * 32 * 256);
  float4* dst4 = (float4*)zs;
#pragma unroll
  for (int i = 0; i < 8; ++i) dst4[t + i * 256] = src[t + i * 256];
  __syncthreads();
  {
    float acc = 0.f;
#pragma unroll 8
    for (int k = 0; k < 32; ++k) {
      float z = zs[k * 256 + t];
      acc = fmaf(z, z, acc);
    }
    atomicAdd(&ZN2[mat * 256 + t], acc);
  }
  int l = t & 63, sub = t >> 6;
  for (int i = 0; i < 4; ++i) {
    int combo = sub * 4 + i;                 // ctg 0..15
    int col = combo * 16 + (l & 15);
    int krow = (l >> 4) * 8;
    unsigned int pk[4];
#pragma unroll
    for (int j = 0; j < 4; ++j) {
      unsigned int lo = f2bf(zs[(krow + 2 * j) * 256 + col]);
      unsigned int hi = f2bf(zs[(krow + 2 * j + 1) * 256 + col]);
      pk[j] = lo | (hi << 16);
    }
    uint4* o = (uint4*)(out + ((size_t)(kt * 16 + combo)) * 512 + l * 8);
    *o = make_uint4(pk[0], pk[1], pk[2], pk[3]);
  }
}

// ---------------------------------------------------------------- x[B,C,H,W] -> xl fp32, Vp bf16(padded), nv2
__global__ __launch_bounds__(256) void k_pre1(const float* __restrict__ X,
                                              float* __restrict__ XL,
                                              ushort* __restrict__ Vp,
                                              float* __restrict__ NV2,
                                              float scale) {
  __shared__ float tile[256 * 33];
  __shared__ float facs[32];
  const int b = blockIdx.x >> 5, h = blockIdx.x & 31;
  const int t = threadIdx.x;
  for (int c0 = 0; c0 < 256; c0 += 8) {
    int c = c0 + (t >> 5), w = t & 31;
    tile[c * 33 + w] = X[((b * 256 + c) * 32 + h) * 32 + w];
  }
  __syncthreads();
  {
    int w = t >> 3, s = t & 7;
    float n2 = 0.f;
#pragma unroll 8
    for (int i = 0; i < 32; ++i) {
      float xv = tile[(s + 8 * i) * 33 + w];
      n2 = fmaf(xv, xv, n2);
    }
    n2 += __shfl_xor(n2, 1); n2 += __shfl_xor(n2, 2); n2 += __shfl_xor(n2, 4);
    float n = sqrtf(fmaxf(n2, EPSF));
    float fac = atanh_fast(fminf(n, CLIP1)) * frcp(n) * scale;
    if (s == 0) {
      facs[w] = fac;
      NV2[blockIdx.x * 32 + w] = fac * fac * n2;
    }
  }
  __syncthreads();
  const int g = t & 63;
  const int pix0 = blockIdx.x * 32;
#pragma unroll
  for (int it = 0; it < 8; ++it) {
    int p = (t >> 6) + it * 4;
    float f = facs[p];
    float4 val;
    val.x = tile[(g * 4 + 0) * 33 + p];
    val.y = tile[(g * 4 + 1) * 33 + p];
    val.z = tile[(g * 4 + 2) * 33 + p];
    val.w = tile[(g * 4 + 3) * 33 + p];
    *(float4*)(XL + (size_t)(pix0 + p) * 256 + g * 4) = val;
    ushort4 vb;
    vb.x = f2bf(val.x * f); vb.y = f2bf(val.y * f);
    vb.z = f2bf(val.z * f); vb.w = f2bf(val.w * f);
    *(ushort4*)(Vp + ((size_t)((b * 34 + h + 1) * 34 + (p + 1))) * 256 + g * 4) = vb;
  }
}

// ---------------------------------------------------------------- 3x3 box sum of nv2
__global__ __launch_bounds__(256) void k_boxsum(const float* __restrict__ NV2,
                                                float* __restrict__ P2) {
  int pix = blockIdx.x * 256 + threadIdx.x;
  int hw = pix & 1023, hh = hw >> 5, ww = hw & 31, base = pix & ~1023;
  float s = 0.f;
#pragma unroll
  for (int di = -1; di <= 1; ++di)
#pragma unroll
    for (int dj = -1; dj <= 1; ++dj) {
      int sh = hh + di, sw = ww + dj;
      if ((unsigned)sh < 32u && (unsigned)sw < 32u) s += NV2[base + sh * 32 + sw];
    }
  P2[pix] = s;
}

// ---------------------------------------------------------------- MFMA implicit-GEMM conv
// tile 128 rows x 64 cols, BK=64, XCD-swizzled 1D grid of 512
__global__ __launch_bounds__(256) void k_gemm_mfma(const ushort* __restrict__ Vp,
                                                   const ushort* __restrict__ ZF,
                                                   float* __restrict__ S) {
  __shared__ ushort lds[24576];  // 2 bufs x (16KB A + 8KB B)
  const int t = threadIdx.x;
  const int w = t >> 6, l = t & 63;
  const int l15 = l & 15, l16 = l >> 4;
  const int g = blockIdx.x;
  const int xcd = g & 7, gi = g >> 3;
  const int rowb = (gi >> 2) * 8 + xcd;   // 0..127
  const int colb = gi & 3;                // 0..3
  const int col0 = colb * 64, row0 = rowb * 128;
  const int cb4 = colb * 4;

  int abase[2];
#pragma unroll
  for (int i = 0; i < 2; ++i) {
    int r = row0 + (w + i * 4) * 16 + l15;
    int b = r >> 10, h = (r >> 5) & 31, wc = r & 31;
    abase[i] = ((b * 34 + h + 1) * 34 + (wc + 1)) * 256 + l16 * 8;
  }

  floatx4 acc[2][4];
#pragma unroll
  for (int i = 0; i < 2; ++i)
#pragma unroll
    for (int j = 0; j < 4; ++j) acc[i][j] = (floatx4){0.f, 0.f, 0.f, 0.f};

  auto stage = [&](int buf, int kt) {
    int tap = kt >> 2, cin0 = (kt & 3) << 6;
    int koff = ((tap / 3 - 1) * 34 + (tap % 3 - 1)) * 256 + cin0;
    ushort* Ad = lds + buf * 12288;
    ushort* Bd = Ad + 8192;
#pragma unroll
    for (int ii = 0; ii < 4; ++ii) {
      int bi = w + ii * 4;
      int s = bi >> 3;
      gl_lds16(Vp + abase[ii & 1] + koff + s * 32, Ad + bi * 512);
    }
#pragma unroll
    for (int ii = 0; ii < 2; ++ii) {
      int bj = w + ii * 4;
      int s = bj >> 2, ct = bj & 3;
      gl_lds16(ZF + ((size_t)((kt * 2 + s) * 16 + cb4 + ct)) * 512 + l * 8,
               Bd + bj * 512);
    }
  };

  auto compute = [&](int buf) {
    const ushort* Ab = lds + buf * 12288;
    const ushort* Bb = Ab + 8192;
    bf16x8 a[2][2], b[2][4];
#pragma unroll
    for (int s = 0; s < 2; ++s) {
#pragma unroll
      for (int i = 0; i < 2; ++i)
        a[s][i] = *(const bf16x8*)(Ab + (s * 8 + w * 2 + i) * 512 + l * 8);
#pragma unroll
      for (int j = 0; j < 4; ++j)
        b[s][j] = *(const bf16x8*)(Bb + (s * 4 + j) * 512 + l * 8);
    }
#pragma unroll
    for (int s = 0; s < 2; ++s)
#pragma unroll
      for (int i = 0; i < 2; ++i)
#pragma unroll
        for (int j = 0; j < 4; ++j)
          acc[i][j] = __builtin_amdgcn_mfma_f32_16x16x32_bf16(a[s][i], b[s][j],
                                                              acc[i][j], 0, 0, 0);
  };

  stage(0, 0);
  for (int kt = 0; kt < 36; ++kt) {
    __syncthreads();
    if (kt + 1 < 36) stage((kt + 1) & 1, kt + 1);
    compute(kt & 1);
  }

#pragma unroll
  for (int i = 0; i < 2; ++i) {
    int r = row0 + w * 32 + i * 16 + l16 * 4;
#pragma unroll
    for (int j = 0; j < 4; ++j) {
      int c = col0 + j * 16 + l15;
#pragma unroll
      for (int reg = 0; reg < 4; ++reg)
        S[(size_t)(r + reg) * 256 + c] = acc[i][j][reg];
    }
  }
}

// ---------------------------------------------------------------- Poincare-FC epilogue + BN reduction 1 (fused)
// 512 blocks x 32 pixels; writes h + per-block NUM/DEN partials
__global__ __launch_bounds__(256) void k_fcepi_red(const float* __restrict__ S,
                                                   const float* __restrict__ P2,
                                                   const float* __restrict__ ZN2,
                                                   float* __restrict__ H,
                                                   float* __restrict__ PNUM,
                                                   float* __restrict__ PDEN) {
  __shared__ float snum[256];
  __shared__ float sden;
  int t = threadIdx.x, lane = t & 63, wv = t >> 6;
  snum[t] = 0.f;
  if (t == 0) sden = 0.f;
  __syncthreads();
  float4 z2 = ((const float4*)ZN2)[lane];
  float zn[4] = {sqrtf(fmaxf(z2.x, EPSF)), sqrtf(fmaxf(z2.y, EPSF)),
                 sqrtf(fmaxf(z2.z, EPSF)), sqrtf(fmaxf(z2.w, EPSF))};
  float izn[4] = {frcp(zn[0]), frcp(zn[1]), frcp(zn[2]), frcp(zn[3])};
  float acc[4] = {0.f, 0.f, 0.f, 0.f};
  float accd = 0.f;
  for (int it = 0; it < 8; ++it) {
    int pix = blockIdx.x * 32 + it * 4 + wv;
    float4 sv = ((const float4*)S)[pix * 64 + lane];
    float p2 = P2[pix];
    float np = sqrtf(fmaxf(p2, EPSF));
    float un = tanh_fast(np);
    float f = un * frcp(np);
    if (un > MAXNRM) f *= MAXNRM / un;
    float u2 = f * f * p2;
    float lamu = 2.f * frcp(fmaxf(1.f - u2, EPSF));
    float lf = lamu * f;
    float sval[4] = {sv.x, sv.y, sv.z, sv.w};
    float y[4];
#pragma unroll
    for (int k = 0; k < 4; ++k)
      y[k] = sinh2zasinh(zn[k], lf * sval[k] * izn[k]);
    float y2 = wred(y[0] * y[0] + y[1] * y[1] + y[2] * y[2] + y[3] * y[3]);
    float inv = frcp(1.f + sqrtf(1.f + y2));
    float h[4] = {y[0] * inv, y[1] * inv, y[2] * inv, y[3] * inv};
    ((float4*)H)[pix * 64 + lane] = make_float4(h[0], h[1], h[2], h[3]);
    float hn2 = y2 * inv * inv;
    float lam = 2.f * frcp(fmaxf(1.f - hn2, EPSF));
#pragma unroll
    for (int k = 0; k < 4; ++k) acc[k] = fmaf(lam, h[k], acc[k]);
    if (lane == 0) accd += lam - 1.f;
  }
  atomicAdd(&snum[lane * 4 + 0], acc[0]);
  atomicAdd(&snum[lane * 4 + 1], acc[1]);
  atomicAdd(&snum[lane * 4 + 2], acc[2]);
  atomicAdd(&snum[lane * 4 + 3], acc[3]);
  if (lane == 0) atomicAdd(&sden, accd);
  __syncthreads();
  PNUM[t * 512 + blockIdx.x] = snum[t];
  if (t == 0) PDEN[blockIdx.x] = sden;
}

// ---------------------------------------------------------------- BN midpoint + scalars (reduces partials)
__global__ __launch_bounds__(256) void k_bnmid(const float* __restrict__ PNUM,
                                               const float* __restrict__ PDEN,
                                               const float* __restrict__ BIAS,
                                               float* __restrict__ MU,
                                               float* __restrict__ SCAL) {
  __shared__ float sb[4];
  int t = threadIdx.x, lane = t & 63, wv = t >> 6;
  auto bred = [&](float v) {
    v = wred(v);
    __syncthreads();
    if (lane == 0) sb[wv] = v;
    __syncthreads();
    return sb[0] + sb[1] + sb[2] + sb[3];
  };
  float num = 0.f;
  const float4* pn = (const float4*)(PNUM + t * 512);
#pragma unroll 8
  for (int i = 0; i < 128; ++i) {
    float4 v = pn[i];
    num += (v.x + v.y) + (v.z + v.w);
  }
  float den = bred(PDEN[t] + PDEN[t + 256]);
  float m = num / fmaxf(den, EPSF);
  float n2m = bred(m * m);
  float n = sqrtf(fmaxf(n2m, EPSF));
  float midf = tanh_fast(0.5f * atanh_fast(fminf(n, CLIP1))) * frcp(n);
  float mu = m * midf;
  MU[t] = mu;
  float bv = BIAS[t];
  float bias2 = bred(bv * bv);
  float mubias = bred(bv * mu);
  if (t == 0) {
    float mu2 = midf * midf * n2m;
    SCAL[0] = mu2;
    SCAL[1] = 2.f / fmaxf(1.f - mu2, EPSF);
    SCAL[2] = bias2;
    SCAL[3] = 2.f / fmaxf(1.f - bias2, EPSF);
    SCAL[4] = mubias;
  }
}

// ---------------------------------------------------------------- BN reduction 2 (var) -> per-block partials
__global__ __launch_bounds__(256) void k_bnred2(const float* __restrict__ Hin,
                                                const float* __restrict__ MU,
                                                const float* __restrict__ SCAL,
                                                float* __restrict__ PVAR) {
  __shared__ float sp[4];
  int t = threadIdx.x, lane = t & 63, wv = t >> 6;
  float4 muv = ((const float4*)MU)[lane];
  float mu2 = SCAL[0];
  float accd = 0.f;
  for (int it = 0; it < 8; ++it) {
    int pix = blockIdx.x * 32 + it * 4 + wv;
    float4 hv = ((const float4*)Hin)[pix * 64 + lane];
    float x2 = wred(hv.x * hv.x + hv.y * hv.y + hv.z * hv.z + hv.w * hv.w);
    float xmu = wred(hv.x * muv.x + hv.y * muv.y + hv.z * muv.z + hv.w * muv.w);
    float A = 1.f - 2.f * xmu + mu2;
    float B = 1.f - x2;
    float num2 = A * A * x2 + B * B * mu2 - 2.f * A * B * xmu;
    float den = fmaxf(1.f - 2.f * xmu + x2 * mu2, EPSF);
    float nn = sqrtf(fmaxf(num2, EPSF)) * frcp(den);
    float dist = 2.f * atanh_fast(fminf(nn, CLIP1));
    accd += dist * dist;
  }
  if (lane == 0) sp[wv] = accd;
  __syncthreads();
  if (t == 0) PVAR[blockIdx.x] = sp[0] + sp[1] + sp[2] + sp[3];
}

// ---------------------------------------------------------------- BN transform core
template <bool CLIPR>
__device__ __forceinline__ void bn_core(const float x[4], const float mm[4],
                                        const float bs[4], float mu2, float lam_mu,
                                        float bias2, float lam_bias, float mubias,
                                        float rstd, float r[4], float& nr) {
  float x2 = wred(x[0] * x[0] + x[1] * x[1] + x[2] * x[2] + x[3] * x[3]);
  float xmu = wred(x[0] * mm[0] + x[1] * mm[1] + x[2] * mm[2] + x[3] * mm[3]);
  float P = 1.f - 2.f * xmu + x2, Q = 1.f - mu2;
  float den1i = frcp(fmaxf(1.f - 2.f * xmu + mu2 * x2, EPSF));
  float d[4];
#pragma unroll
  for (int k = 0; k < 4; ++k) d[k] = (Q * x[k] - P * mm[k]) * den1i;
  float nd2 = wred(d[0] * d[0] + d[1] * d[1] + d[2] * d[2] + d[3] * d[3]);
  float nd = sqrtf(fmaxf(nd2, EPSF));
  float vfac = (2.f / lam_mu) * atanh_fast(fminf(nd, CLIP1)) * frcp(nd);
  float v[4];
#pragma unroll
  for (int k = 0; k < 4; ++k) v[k] = vfac * d[k];
  float uw = wred(bs[0] * v[0] + bs[1] * v[1] + bs[2] * v[2] + bs[3] * v[3]);
  float mv = wred(mm[0] * v[0] + mm[1] * v[1] + mm[2] * v[2] + mm[3] * v[3]);
  float vw = -mv, uv = -mubias;
  float ga = -(uw * mu2) - vw + 2.f * uv * vw;
  float gb = -(vw * bias2) + uw;
  float ddi = frcp(fmaxf(1.f + 2.f * uv + bias2 * mu2, EPSF));
  float sgy = (lam_mu / lam_bias) * rstd;
  float u[4];
#pragma unroll
  for (int k = 0; k < 4; ++k)
    u[k] = (v[k] + 2.f * (ga * bs[k] - gb * mm[k]) * ddi) * sgy;
  float nu2 = wred(u[0] * u[0] + u[1] * u[1] + u[2] * u[2] + u[3] * u[3]);
  float bu = wred(bs[0] * u[0] + bs[1] * u[1] + bs[2] * u[2] + bs[3] * u[3]);
  float nu = sqrtf(fmaxf(nu2, EPSF));
  float sfac = tanh_fast(lam_bias * nu * 0.5f) * frcp(nu);
  float y2 = sfac * sfac * nu2, xy = sfac * bu;
  float P2 = 1.f + 2.f * xy + y2, Q2 = 1.f - bias2;
  float den2i = frcp(fmaxf(1.f + 2.f * xy + bias2 * y2, EPSF));
#pragma unroll
  for (int k = 0; k < 4; ++k) r[k] = (P2 * bs[k] + Q2 * sfac * u[k]) * den2i;
  float nr2 = wred(r[0] * r[0] + r[1] * r[1] + r[2] * r[2] + r[3] * r[3]);
  nr = sqrtf(fmaxf(nr2, EPSF));
  if (CLIPR && nr > MAXNRM) {
    float sc = MAXNRM / nr;
#pragma unroll
    for (int k = 0; k < 4; ++k) r[k] *= sc;
    nr = MAXNRM;
  }
}

// reduce 512 PVAR partials to var (all threads get result)
__device__ __forceinline__ float pvar_reduce(const float* PVAR, float* sbv) {
  int t = threadIdx.x, lane = t & 63, wv = t >> 6;
  float pv = wred(PVAR[t] + PVAR[t + 256]);
  if (lane == 0) sbv[wv] = pv;
  __syncthreads();
  return (sbv[0] + sbv[1] + sbv[2] + sbv[3]) * (1.f / 16384.f);
}

// ---------------------------------------------------------------- BN1 transform + hrelu + logmap0*scale -> Vp,NV2
__global__ __launch_bounds__(256) void k_bntrans_pre(const float* __restrict__ Hin,
                                                     const float* __restrict__ MU,
                                                     const float* __restrict__ SCAL,
                                                     const float* __restrict__ BIAS,
                                                     const float* __restrict__ WEIGHT,
                                                     const float* __restrict__ PVAR,
                                                     ushort* __restrict__ Vp,
                                                     float* __restrict__ NV2,
                                                     float scale) {
  __shared__ float sbv[4];
  int pix = blockIdx.x * 4 + (threadIdx.x >> 6);
  int lane = threadIdx.x & 63;
  float var = pvar_reduce(PVAR, sbv);
  float4 xv4 = ((const float4*)Hin)[pix * 64 + lane];
  float4 mu4 = ((const float4*)MU)[lane];
  float4 bb4 = ((const float4*)BIAS)[lane];
  float mu2 = SCAL[0], lam_mu = SCAL[1], bias2 = SCAL[2], lam_bias = SCAL[3],
        mubias = SCAL[4];
  float rstd = sqrtf(WEIGHT[0] / fmaxf(var, EPSF));
  float x[4] = {xv4.x, xv4.y, xv4.z, xv4.w};
  float mm[4] = {mu4.x, mu4.y, mu4.z, mu4.w};
  float bs[4] = {bb4.x, bb4.y, bb4.z, bb4.w};
  float r[4], nr;
  bn_core<true>(x, mm, bs, mu2, lam_mu, bias2, lam_bias, mubias, rstd, r, nr);
  float tf = atanh_fast(fminf(nr, CLIP1)) * frcp(nr);
  float tr[4];
#pragma unroll
  for (int k = 0; k < 4; ++k) tr[k] = fmaxf(tf * r[k], 0.f);
  float nt2 = wred(tr[0] * tr[0] + tr[1] * tr[1] + tr[2] * tr[2] + tr[3] * tr[3]);
  int b = pix >> 10, hh = (pix >> 5) & 31, ww = pix & 31;
  ushort4 vb;
  vb.x = f2bf(tr[0] * scale); vb.y = f2bf(tr[1] * scale);
  vb.z = f2bf(tr[2] * scale); vb.w = f2bf(tr[3] * scale);
  *(ushort4*)(Vp + ((size_t)((b * 34 + hh + 1) * 34 + (ww + 1))) * 256 + lane * 4) = vb;
  if (lane == 0) NV2[pix] = nt2 * scale * scale;
}

// ---------------------------------------------------------------- BN2 transform + residual + hrelu + [B,C,H,W] store
__global__ __launch_bounds__(256) void k_bntrans_out(const float* __restrict__ Hin,
                                                     const float* __restrict__ MU,
                                                     const float* __restrict__ SCAL,
                                                     const float* __restrict__ BIAS,
                                                     const float* __restrict__ WEIGHT,
                                                     const float* __restrict__ PVAR,
                                                     const float* __restrict__ RES,
                                                     float* __restrict__ Out) {
  __shared__ float tile[256 * 33];
  __shared__ float sbv[4];
  int t = threadIdx.x, lane = t & 63, wv = t >> 6;
  float var = pvar_reduce(PVAR, sbv);
  float4 mu4 = ((const float4*)MU)[lane];
  float4 bb4 = ((const float4*)BIAS)[lane];
  float mu2 = SCAL[0], lam_mu = SCAL[1], bias2 = SCAL[2], lam_bias = SCAL[3],
        mubias = SCAL[4];
  float rstd = sqrtf(WEIGHT[0] / fmaxf(var, EPSF));
  float mm[4] = {mu4.x, mu4.y, mu4.z, mu4.w};
  float bs[4] = {bb4.x, bb4.y, bb4.z, bb4.w};
  int pix0 = blockIdx.x * 32;
  for (int it = 0; it < 8; ++it) {
    int p = it * 4 + wv;
    int pix = pix0 + p;
    float4 xv4 = ((const float4*)Hin)[pix * 64 + lane];
    float x[4] = {xv4.x, xv4.y, xv4.z, xv4.w};
    float r[4], nr;
    bn_core<true>(x, mm, bs, mu2, lam_mu, bias2, lam_bias, mubias, rstd, r, nr);
    float h2 = nr * nr;
    float4 rs4 = ((const float4*)RES)[pix * 64 + lane];
    float rr[4] = {rs4.x, rs4.y, rs4.z, rs4.w};
    float y2r = wred(rr[0] * rr[0] + rr[1] * rr[1] + rr[2] * rr[2] + rr[3] * rr[3]);
    float xyr = wred(r[0] * rr[0] + r[1] * rr[1] + r[2] * rr[2] + r[3] * rr[3]);
    float Pm = 1.f + 2.f * xyr + y2r, Qm = 1.f - h2;
    float denmi = frcp(fmaxf(1.f + 2.f * xyr + h2 * y2r, EPSF));
#pragma unroll
    for (int k = 0; k < 4; ++k) r[k] = (Pm * r[k] + Qm * rr[k]) * denmi;
    float nr2 = wred(r[0] * r[0] + r[1] * r[1] + r[2] * r[2] + r[3] * r[3]);
    nr = sqrtf(fmaxf(nr2, EPSF));
    float tf = atanh_fast(fminf(nr, CLIP1)) * frcp(nr);
    float tr[4];
#pragma unroll
    for (int k = 0; k < 4; ++k) tr[k] = fmaxf(tf * r[k], 0.f);
    float nt2 = wred(tr[0] * tr[0] + tr[1] * tr[1] + tr[2] * tr[2] + tr[3] * tr[3]);
    float nt = sqrtf(fmaxf(nt2, EPSF));
    float une = tanh_fast(nt);
    float ef = une * frcp(nt);
    if (une > MAXNRM) ef *= MAXNRM / une;
#pragma unroll
    for (int k = 0; k < 4; ++k) tile[(lane * 4 + k) * 33 + p] = ef * tr[k];
  }
  __syncthreads();
  int b = blockIdx.x >> 5, h = blockIdx.x & 31;
  for (int c0 = 0; c0 < 256; c0 += 8) {
    int c = c0 + (t >> 5), w = t & 31;
    Out[((b * 256 + c) * 32 + h) * 32 + w] = tile[c * 33 + w];
  }
}

// ---------------------------------------------------------------- launch
extern "C" void kernel_launch(void* const* d_in, const int* in_sizes, int n_in,
                              void* d_out, int out_size, void* d_ws, size_t ws_size,
                              hipStream_t stream) {
  (void)in_sizes; (void)n_in; (void)out_size; (void)ws_size;
  const float* x  = (const float*)d_in[0];
  const float* z1 = (const float*)d_in[1];
  const float* z2 = (const float*)d_in[2];
  const float* w1 = (const float*)d_in[3];
  const float* b1 = (const float*)d_in[4];
  const float* w2 = (const float*)d_in[5];
  const float* b2 = (const float*)d_in[6];
  float* out = (float*)d_out;
  float* ws = (float*)d_ws;

  float* zn2   = ws;            // 512
  float* mu    = ws + 768;      // 256
  float* scal  = ws + 1024;     // 8
  float* pden  = ws + 1088;     // 512
  float* pvar  = ws + 1664;     // 512
  float* pnum  = ws + 2560;     // 256*512 = 131072
  float* nv2   = ws + 133632;   // 16384
  float* p2    = ws + 150016;   // 16384
  float* xl    = ws + 166400;   // 16 MB
  float* h     = xl + 4194304;  // 16 MB
  float* s     = h + 4194304;   // 16 MB
  ushort* Vp   = (ushort*)(s + 4194304);  // 16*34*34*256 bf16 = 9.47 MB
  ushort* ZF   = Vp + 4734976;            // 2 x 589824 bf16

  double lb = (lgamma(1152.0) - lgamma(1152.5)) - (lgamma(128.0) - lgamma(128.5));
  float scale = (float)exp(lb);

  hipMemsetAsync(ws, 0, 512 * sizeof(float), stream);     // zn2
  hipMemsetAsync(Vp, 0, (size_t)4734976 * 2, stream);     // zero padding borders
  k_zpack<<<dim3(72, 2), 256, 0, stream>>>(z1, z2, ZF, zn2);

  // ---- conv1
  k_pre1<<<512, 256, 0, stream>>>(x, xl, Vp, nv2, scale);
  k_boxsum<<<64, 256, 0, stream>>>(nv2, p2);
  k_gemm_mfma<<<512, 256, 0, stream>>>(Vp, ZF, s);
  k_fcepi_red<<<512, 256, 0, stream>>>(s, p2, zn2, h, pnum, pden);
  k_bnmid<<<1, 256, 0, stream>>>(pnum, pden, b1, mu, scal);
  k_bnred2<<<512, 256, 0, stream>>>(h, mu, scal, pvar);
  k_bntrans_pre<<<4096, 256, 0, stream>>>(h, mu, scal, b1, w1, pvar, Vp, nv2, scale);

  // ---- conv2
  k_boxsum<<<64, 256, 0, stream>>>(nv2, p2);
  k_gemm_mfma<<<512, 256, 0, stream>>>(Vp, ZF + 589824, s);
  k_fcepi_red<<<512, 256, 0, stream>>>(s, p2, zn2 + 256, h, pnum, pden);
  k_bnmid<<<1, 256, 0, stream>>>(pnum, pden, b2, mu, scal);
  k_bnred2<<<512, 256, 0, stream>>>(h, mu, scal, pvar);
  k_bntrans_out<<<512, 256, 0, stream>>>(h, mu, scal, b2, w2, pvar, xl, out);
}

// Round 7
// 293.652 us; speedup vs baseline: 1.3582x; 1.0018x over previous
//
#include <hip/hip_runtime.h>
#include <math.h>

#define EPSF   1e-15f
#define CLIP1  0.99999988f   /* fp32(1 - 1e-7) */
#define MAXNRM 0.99999f      /* (1 - 1e-5)/sqrt(c), c = 1 */
#define LOG2E  1.44269504088896f
#define LN2    0.69314718055994f

typedef __bf16 bf16x8 __attribute__((ext_vector_type(8)));
typedef float floatx4 __attribute__((ext_vector_type(4)));
typedef _Float16 half4 __attribute__((ext_vector_type(4)));

// ---------------------------------------------------------------- utilities
__device__ __forceinline__ float wred(float x) {
#pragma unroll
  for (int o = 32; o; o >>= 1) x += __shfl_xor(x, o);
  return x;
}

__device__ __forceinline__ float frcp(float x) { return __builtin_amdgcn_rcpf(x); }
__device__ __forceinline__ float flog2(float x) { return __builtin_amdgcn_logf(x); }
__device__ __forceinline__ float fexp2(float x) { return __builtin_amdgcn_exp2f(x); }

__device__ __forceinline__ float atanh_fast(float x) {   // x in [0, CLIP1]
  return 0.5f * LN2 * flog2((1.f + x) * frcp(1.f - x));
}
__device__ __forceinline__ float tanh_fast(float x) {    // x >= 0
  float q = fexp2(fminf(2.f * LOG2E * x, 126.f));
  return (q - 1.f) * frcp(q + 1.f);
}
// sinh(2*z*asinh(w)), z > 0
__device__ __forceinline__ float sinh2zasinh(float z, float w) {
  float aw = fabsf(w);
  float tt = aw + sqrtf(fmaf(aw, aw, 1.f));
  float k2 = fminf(2.f * z * flog2(tt), 126.f);
  float q = fexp2(k2);
  return copysignf(0.5f * (q - frcp(q)), w);
}

__device__ __forceinline__ unsigned short f2bf(float f) {
  unsigned int u = __float_as_uint(f);
  u += 0x7fffu + ((u >> 16) & 1u);   // RNE
  return (unsigned short)(u >> 16);
}

__device__ __forceinline__ void gl_lds16(const ushort* g, ushort* l) {
  __builtin_amdgcn_global_load_lds(
      (const __attribute__((address_space(1))) void*)g,
      (__attribute__((address_space(3))) void*)l, 16, 0, 0);
}

// ---------------------------------------------------------------- Z -> fragment-ordered bf16 (+ column norms^2)
__global__ __launch_bounds__(256) void k_zpack(const float* __restrict__ Z1,
                                               const float* __restrict__ Z2,
                                               ushort* __restrict__ ZF,
                                               float* __restrict__ ZN2) {
  __shared__ float zs[32 * 256];
  int kt = blockIdx.x, mat = blockIdx.y;
  const float* Z = mat ? Z2 : Z1;
  ushort* out = ZF + (size_t)mat * 589824;
  int t = threadIdx.x;
  const float4* src = (const float4*)(Z + kt * 32 * 256);
  float4* dst4 = (float4*)zs;
#pragma unroll
  for (int i = 0; i < 8; ++i) dst4[t + i * 256] = src[t + i * 256];
  __syncthreads();
  {
    float acc = 0.f;
#pragma unroll 8
    for (int k = 0; k < 32; ++k) {
      float z = zs[k * 256 + t];
      acc = fmaf(z, z, acc);
    }
    atomicAdd(&ZN2[mat * 256 + t], acc);
  }
  int l = t & 63, sub = t >> 6;
  for (int i = 0; i < 4; ++i) {
    int combo = sub * 4 + i;                 // ctg 0..15
    int col = combo * 16 + (l & 15);
    int krow = (l >> 4) * 8;
    unsigned int pk[4];
#pragma unroll
    for (int j = 0; j < 4; ++j) {
      unsigned int lo = f2bf(zs[(krow + 2 * j) * 256 + col]);
      unsigned int hi = f2bf(zs[(krow + 2 * j + 1) * 256 + col]);
      pk[j] = lo | (hi << 16);
    }
    uint4* o = (uint4*)(out + ((size_t)(kt * 16 + combo)) * 512 + l * 8);
    *o = make_uint4(pk[0], pk[1], pk[2], pk[3]);
  }
}

// ---------------------------------------------------------------- x[B,C,H,W] -> xl fp32, Vp bf16(padded), nv2
__global__ __launch_bounds__(256) void k_pre1(const float* __restrict__ X,
                                              float* __restrict__ XL,
                                              ushort* __restrict__ Vp,
                                              float* __restrict__ NV2,
                                              float scale) {
  __shared__ float tile[256 * 33];
  __shared__ float facs[32];
  const int b = blockIdx.x >> 5, h = blockIdx.x & 31;
  const int t = threadIdx.x;
  for (int c0 = 0; c0 < 256; c0 += 8) {
    int c = c0 + (t >> 5), w = t & 31;
    tile[c * 33 + w] = X[((b * 256 + c) * 32 + h) * 32 + w];
  }
  __syncthreads();
  {
    int w = t >> 3, s = t & 7;
    float n2 = 0.f;
#pragma unroll 8
    for (int i = 0; i < 32; ++i) {
      float xv = tile[(s + 8 * i) * 33 + w];
      n2 = fmaf(xv, xv, n2);
    }
    n2 += __shfl_xor(n2, 1); n2 += __shfl_xor(n2, 2); n2 += __shfl_xor(n2, 4);
    float n = sqrtf(fmaxf(n2, EPSF));
    float fac = atanh_fast(fminf(n, CLIP1)) * frcp(n) * scale;
    if (s == 0) {
      facs[w] = fac;
      NV2[blockIdx.x * 32 + w] = fac * fac * n2;
    }
  }
  __syncthreads();
  const int g = t & 63;
  const int pix0 = blockIdx.x * 32;
#pragma unroll
  for (int it = 0; it < 8; ++it) {
    int p = (t >> 6) + it * 4;
    float f = facs[p];
    float4 val;
    val.x = tile[(g * 4 + 0) * 33 + p];
    val.y = tile[(g * 4 + 1) * 33 + p];
    val.z = tile[(g * 4 + 2) * 33 + p];
    val.w = tile[(g * 4 + 3) * 33 + p];
    *(float4*)(XL + (size_t)(pix0 + p) * 256 + g * 4) = val;
    ushort4 vb;
    vb.x = f2bf(val.x * f); vb.y = f2bf(val.y * f);
    vb.z = f2bf(val.z * f); vb.w = f2bf(val.w * f);
    *(ushort4*)(Vp + ((size_t)((b * 34 + h + 1) * 34 + (p + 1))) * 256 + g * 4) = vb;
  }
}

// ---------------------------------------------------------------- 3x3 box sum -> LF (lam*f per pixel); zero Y2; ZN/IZN
__global__ __launch_bounds__(256) void k_boxsum(const float* __restrict__ NV2,
                                                const float* __restrict__ ZN2,
                                                float* __restrict__ LF,
                                                float* __restrict__ Y2,
                                                float* __restrict__ ZN,
                                                float* __restrict__ IZN) {
  int pix = blockIdx.x * 256 + threadIdx.x;
  if (blockIdx.x < 2) {
    int idx = blockIdx.x * 256 + threadIdx.x;   // both mats, 512 entries
    float zn = sqrtf(fmaxf(ZN2[idx], EPSF));
    ZN[idx] = zn;
    IZN[idx] = frcp(zn);
  }
  int hw = pix & 1023, hh = hw >> 5, ww = hw & 31, base = pix & ~1023;
  float s = 0.f;
#pragma unroll
  for (int di = -1; di <= 1; ++di)
#pragma unroll
    for (int dj = -1; dj <= 1; ++dj) {
      int sh = hh + di, sw = ww + dj;
      if ((unsigned)sh < 32u && (unsigned)sw < 32u) s += NV2[base + sh * 32 + sw];
    }
  float np = sqrtf(fmaxf(s, EPSF));
  float un = tanh_fast(np);
  float f = un * frcp(np);
  if (un > MAXNRM) f *= MAXNRM / un;
  float u2 = f * f * s;
  float lam = 2.f * frcp(fmaxf(1.f - u2, EPSF));
  LF[pix] = lam * f;
  Y2[pix] = 0.f;
}

// ---------------------------------------------------------------- MFMA implicit-GEMM conv + fused Poincare-FC front half
// tile 128 rows x 64 cols, BK=64, XCD-swizzled; epilogue: y=sinh(2 zn asinh(LF*S/zn)) -> Y fp16, Y2 += y^2
__global__ __launch_bounds__(256) void k_gemm_mfma(const ushort* __restrict__ Vp,
                                                   const ushort* __restrict__ ZF,
                                                   const float* __restrict__ ZN,
                                                   const float* __restrict__ IZN,
                                                   const float* __restrict__ LF,
                                                   _Float16* __restrict__ Y,
                                                   float* __restrict__ Y2) {
  __shared__ ushort lds[24576];  // 2 bufs x (16KB A + 8KB B)
  const int t = threadIdx.x;
  const int w = t >> 6, l = t & 63;
  const int l15 = l & 15, l16 = l >> 4;
  const int g = blockIdx.x;
  const int xcd = g & 7, gi = g >> 3;
  const int rowb = (gi >> 2) * 8 + xcd;   // 0..127
  const int colb = gi & 3;                // 0..3
  const int col0 = colb * 64, row0 = rowb * 128;
  const int cb4 = colb * 4;

  int abase[2];
#pragma unroll
  for (int i = 0; i < 2; ++i) {
    int r = row0 + (w + i * 4) * 16 + l15;
    int b = r >> 10, h = (r >> 5) & 31, wc = r & 31;
    abase[i] = ((b * 34 + h + 1) * 34 + (wc + 1)) * 256 + l16 * 8;
  }

  floatx4 acc[2][4];
#pragma unroll
  for (int i = 0; i < 2; ++i)
#pragma unroll
    for (int j = 0; j < 4; ++j) acc[i][j] = (floatx4){0.f, 0.f, 0.f, 0.f};

  auto stage = [&](int buf, int kt) {
    int tap = kt >> 2, cin0 = (kt & 3) << 6;
    int koff = ((tap / 3 - 1) * 34 + (tap % 3 - 1)) * 256 + cin0;
    ushort* Ad = lds + buf * 12288;
    ushort* Bd = Ad + 8192;
#pragma unroll
    for (int ii = 0; ii < 4; ++ii) {
      int bi = w + ii * 4;
      int s = bi >> 3;
      gl_lds16(Vp + abase[ii & 1] + koff + s * 32, Ad + bi * 512);
    }
#pragma unroll
    for (int ii = 0; ii < 2; ++ii) {
      int bj = w + ii * 4;
      int s = bj >> 2, ct = bj & 3;
      gl_lds16(ZF + ((size_t)((kt * 2 + s) * 16 + cb4 + ct)) * 512 + l * 8,
               Bd + bj * 512);
    }
  };

  auto compute = [&](int buf) {
    const ushort* Ab = lds + buf * 12288;
    const ushort* Bb = Ab + 8192;
    bf16x8 a[2][2], b[2][4];
#pragma unroll
    for (int s = 0; s < 2; ++s) {
#pragma unroll
      for (int i = 0; i < 2; ++i)
        a[s][i] = *(const bf16x8*)(Ab + (s * 8 + w * 2 + i) * 512 + l * 8);
#pragma unroll
      for (int j = 0; j < 4; ++j)
        b[s][j] = *(const bf16x8*)(Bb + (s * 4 + j) * 512 + l * 8);
    }
#pragma unroll
    for (int s = 0; s < 2; ++s)
#pragma unroll
      for (int i = 0; i < 2; ++i)
#pragma unroll
        for (int j = 0; j < 4; ++j)
          acc[i][j] = __builtin_amdgcn_mfma_f32_16x16x32_bf16(a[s][i], b[s][j],
                                                              acc[i][j], 0, 0, 0);
  };

  stage(0, 0);
  for (int kt = 0; kt < 36; ++kt) {
    __syncthreads();
    if (kt + 1 < 36) stage((kt + 1) & 1, kt + 1);
    compute(kt & 1);
  }

  // fused epilogue: y + per-pixel y^2 partials
  float zns[4], izns[4];
#pragma unroll
  for (int j = 0; j < 4; ++j) {
    int c = col0 + j * 16 + l15;
    zns[j] = ZN[c];
    izns[j] = IZN[c];
  }
#pragma unroll
  for (int i = 0; i < 2; ++i) {
#pragma unroll
    for (int reg = 0; reg < 4; ++reg) {
      int r = row0 + w * 32 + i * 16 + l16 * 4 + reg;
      float lf = LF[r];
      float part = 0.f;
#pragma unroll
      for (int j = 0; j < 4; ++j) {
        float yv = sinh2zasinh(zns[j], lf * acc[i][j][reg] * izns[j]);
        Y[(size_t)r * 256 + col0 + j * 16 + l15] = (_Float16)yv;
        part = fmaf(yv, yv, part);
      }
      part += __shfl_xor(part, 1);
      part += __shfl_xor(part, 2);
      part += __shfl_xor(part, 4);
      part += __shfl_xor(part, 8);
      if (l15 == 0) atomicAdd(&Y2[r], part);
    }
  }
}

// ---------------------------------------------------------------- recompute h from (Y, Y2): h = y/(1+sqrt(1+y2))
__device__ __forceinline__ void load_h(const _Float16* Y, const float* Y2,
                                       int pix, int lane, float h[4],
                                       float& hn2, float& lam) {
  half4 y4 = ((const half4*)Y)[pix * 64 + lane];
  float y2 = Y2[pix];
  float inv = frcp(1.f + sqrtf(1.f + y2));
  h[0] = (float)y4.x * inv; h[1] = (float)y4.y * inv;
  h[2] = (float)y4.z * inv; h[3] = (float)y4.w * inv;
  hn2 = y2 * inv * inv;
  lam = 2.f * frcp(fmaxf(1.f - hn2, EPSF));
}

// ---------------------------------------------------------------- BN reduction 1 (num/den partials)
__global__ __launch_bounds__(256) void k_bnsum(const _Float16* __restrict__ Y,
                                               const float* __restrict__ Y2,
                                               float* __restrict__ PNUM,
                                               float* __restrict__ PDEN) {
  __shared__ float snum[256];
  __shared__ float sden;
  int t = threadIdx.x, lane = t & 63, wv = t >> 6;
  snum[t] = 0.f;
  if (t == 0) sden = 0.f;
  __syncthreads();
  float acc[4] = {0.f, 0.f, 0.f, 0.f};
  float accd = 0.f;
  for (int it = 0; it < 8; ++it) {
    int pix = blockIdx.x * 32 + it * 4 + wv;
    float h[4], hn2, lam;
    load_h(Y, Y2, pix, lane, h, hn2, lam);
#pragma unroll
    for (int k = 0; k < 4; ++k) acc[k] = fmaf(lam, h[k], acc[k]);
    if (lane == 0) accd += lam - 1.f;
  }
  atomicAdd(&snum[lane * 4 + 0], acc[0]);
  atomicAdd(&snum[lane * 4 + 1], acc[1]);
  atomicAdd(&snum[lane * 4 + 2], acc[2]);
  atomicAdd(&snum[lane * 4 + 3], acc[3]);
  if (lane == 0) atomicAdd(&sden, accd);
  __syncthreads();
  PNUM[t * 512 + blockIdx.x] = snum[t];
  if (t == 0) PDEN[blockIdx.x] = sden;
}

// ---------------------------------------------------------------- BN midpoint + scalars (reduces partials)
__global__ __launch_bounds__(256) void k_bnmid(const float* __restrict__ PNUM,
                                               const float* __restrict__ PDEN,
                                               const float* __restrict__ BIAS,
                                               float* __restrict__ MU,
                                               float* __restrict__ SCAL) {
  __shared__ float sb[4];
  int t = threadIdx.x, lane = t & 63, wv = t >> 6;
  auto bred = [&](float v) {
    v = wred(v);
    __syncthreads();
    if (lane == 0) sb[wv] = v;
    __syncthreads();
    return sb[0] + sb[1] + sb[2] + sb[3];
  };
  float num = 0.f;
  const float4* pn = (const float4*)(PNUM + t * 512);
#pragma unroll 8
  for (int i = 0; i < 128; ++i) {
    float4 v = pn[i];
    num += (v.x + v.y) + (v.z + v.w);
  }
  float den = bred(PDEN[t] + PDEN[t + 256]);
  float m = num / fmaxf(den, EPSF);
  float n2m = bred(m * m);
  float n = sqrtf(fmaxf(n2m, EPSF));
  float midf = tanh_fast(0.5f * atanh_fast(fminf(n, CLIP1))) * frcp(n);
  float mu = m * midf;
  MU[t] = mu;
  float bv = BIAS[t];
  float bias2 = bred(bv * bv);
  float mubias = bred(bv * mu);
  if (t == 0) {
    float mu2 = midf * midf * n2m;
    SCAL[0] = mu2;
    SCAL[1] = 2.f / fmaxf(1.f - mu2, EPSF);
    SCAL[2] = bias2;
    SCAL[3] = 2.f / fmaxf(1.f - bias2, EPSF);
    SCAL[4] = mubias;
  }
}

// ---------------------------------------------------------------- BN reduction 2 (var partials)
__global__ __launch_bounds__(256) void k_bnvar(const _Float16* __restrict__ Y,
                                               const float* __restrict__ Y2,
                                               const float* __restrict__ MU,
                                               const float* __restrict__ SCAL,
                                               float* __restrict__ PVAR) {
  __shared__ float sp[4];
  int t = threadIdx.x, lane = t & 63, wv = t >> 6;
  float4 muv = ((const float4*)MU)[lane];
  float mu2 = SCAL[0];
  float accd = 0.f;
  for (int it = 0; it < 8; ++it) {
    int pix = blockIdx.x * 32 + it * 4 + wv;
    float h[4], x2, lam;
    load_h(Y, Y2, pix, lane, h, x2, lam);
    float xmu = wred(h[0] * muv.x + h[1] * muv.y + h[2] * muv.z + h[3] * muv.w);
    float A = 1.f - 2.f * xmu + mu2;
    float B = 1.f - x2;
    float num2 = A * A * x2 + B * B * mu2 - 2.f * A * B * xmu;
    float den = fmaxf(1.f - 2.f * xmu + x2 * mu2, EPSF);
    float nn = sqrtf(fmaxf(num2, EPSF)) * frcp(den);
    float dist = 2.f * atanh_fast(fminf(nn, CLIP1));
    accd += dist * dist;
  }
  if (lane == 0) sp[wv] = accd;
  __syncthreads();
  if (t == 0) PVAR[blockIdx.x] = sp[0] + sp[1] + sp[2] + sp[3];
}

// ---------------------------------------------------------------- BN transform core
template <bool CLIPR>
__device__ __forceinline__ void bn_core(const float x[4], const float mm[4],
                                        const float bs[4], float mu2, float lam_mu,
                                        float bias2, float lam_bias, float mubias,
                                        float rstd, float r[4], float& nr) {
  float x2 = wred(x[0] * x[0] + x[1] * x[1] + x[2] * x[2] + x[3] * x[3]);
  float xmu = wred(x[0] * mm[0] + x[1] * mm[1] + x[2] * mm[2] + x[3] * mm[3]);
  float P = 1.f - 2.f * xmu + x2, Q = 1.f - mu2;
  float den1i = frcp(fmaxf(1.f - 2.f * xmu + mu2 * x2, EPSF));
  float d[4];
#pragma unroll
  for (int k = 0; k < 4; ++k) d[k] = (Q * x[k] - P * mm[k]) * den1i;
  float nd2 = wred(d[0] * d[0] + d[1] * d[1] + d[2] * d[2] + d[3] * d[3]);
  float nd = sqrtf(fmaxf(nd2, EPSF));
  float vfac = (2.f / lam_mu) * atanh_fast(fminf(nd, CLIP1)) * frcp(nd);
  float v[4];
#pragma unroll
  for (int k = 0; k < 4; ++k) v[k] = vfac * d[k];
  float uw = wred(bs[0] * v[0] + bs[1] * v[1] + bs[2] * v[2] + bs[3] * v[3]);
  float mv = wred(mm[0] * v[0] + mm[1] * v[1] + mm[2] * v[2] + mm[3] * v[3]);
  float vw = -mv, uv = -mubias;
  float ga = -(uw * mu2) - vw + 2.f * uv * vw;
  float gb = -(vw * bias2) + uw;
  float ddi = frcp(fmaxf(1.f + 2.f * uv + bias2 * mu2, EPSF));
  float sgy = (lam_mu / lam_bias) * rstd;
  float u[4];
#pragma unroll
  for (int k = 0; k < 4; ++k)
    u[k] = (v[k] + 2.f * (ga * bs[k] - gb * mm[k]) * ddi) * sgy;
  float nu2 = wred(u[0] * u[0] + u[1] * u[1] + u[2] * u[2] + u[3] * u[3]);
  float bu = wred(bs[0] * u[0] + bs[1] * u[1] + bs[2] * u[2] + bs[3] * u[3]);
  float nu = sqrtf(fmaxf(nu2, EPSF));
  float sfac = tanh_fast(lam_bias * nu * 0.5f) * frcp(nu);
  float y2 = sfac * sfac * nu2, xy = sfac * bu;
  float P2 = 1.f + 2.f * xy + y2, Q2 = 1.f - bias2;
  float den2i = frcp(fmaxf(1.f + 2.f * xy + bias2 * y2, EPSF));
#pragma unroll
  for (int k = 0; k < 4; ++k) r[k] = (P2 * bs[k] + Q2 * sfac * u[k]) * den2i;
  float nr2 = wred(r[0] * r[0] + r[1] * r[1] + r[2] * r[2] + r[3] * r[3]);
  nr = sqrtf(fmaxf(nr2, EPSF));
  if (CLIPR && nr > MAXNRM) {
    float sc = MAXNRM / nr;
#pragma unroll
    for (int k = 0; k < 4; ++k) r[k] *= sc;
    nr = MAXNRM;
  }
}

// reduce 512 PVAR partials to var (all threads get result)
__device__ __forceinline__ float pvar_reduce(const float* PVAR, float* sbv) {
  int t = threadIdx.x, lane = t & 63, wv = t >> 6;
  float pv = wred(PVAR[t] + PVAR[t + 256]);
  __syncthreads();
  if (lane == 0) sbv[wv] = pv;
  __syncthreads();
  return (sbv[0] + sbv[1] + sbv[2] + sbv[3]) * (1.f / 16384.f);
}

// ---------------------------------------------------------------- BN1 transform + hrelu + logmap0*scale -> Vp,NV2
__global__ __launch_bounds__(256) void k_bntrans_pre(const _Float16* __restrict__ Y,
                                                     const float* __restrict__ Y2,
                                                     const float* __restrict__ MU,
                                                     const float* __restrict__ SCAL,
                                                     const float* __restrict__ BIAS,
                                                     const float* __restrict__ WEIGHT,
                                                     const float* __restrict__ PVAR,
                                                     ushort* __restrict__ Vp,
                                                     float* __restrict__ NV2,
                                                     float scale) {
  __shared__ float sbv[4];
  int pix = blockIdx.x * 4 + (threadIdx.x >> 6);
  int lane = threadIdx.x & 63;
  float var = pvar_reduce(PVAR, sbv);
  float4 mu4 = ((const float4*)MU)[lane];
  float4 bb4 = ((const float4*)BIAS)[lane];
  float mu2 = SCAL[0], lam_mu = SCAL[1], bias2 = SCAL[2], lam_bias = SCAL[3],
        mubias = SCAL[4];
  float rstd = sqrtf(WEIGHT[0] / fmaxf(var, EPSF));
  float x[4], hn2, lamx;
  load_h(Y, Y2, pix, lane, x, hn2, lamx);
  float mm[4] = {mu4.x, mu4.y, mu4.z, mu4.w};
  float bs[4] = {bb4.x, bb4.y, bb4.z, bb4.w};
  float r[4], nr;
  bn_core<true>(x, mm, bs, mu2, lam_mu, bias2, lam_bias, mubias, rstd, r, nr);
  float tf = atanh_fast(fminf(nr, CLIP1)) * frcp(nr);
  float tr[4];
#pragma unroll
  for (int k = 0; k < 4; ++k) tr[k] = fmaxf(tf * r[k], 0.f);
  float nt2 = wred(tr[0] * tr[0] + tr[1] * tr[1] + tr[2] * tr[2] + tr[3] * tr[3]);
  int b = pix >> 10, hh = (pix >> 5) & 31, ww = pix & 31;
  ushort4 vb;
  vb.x = f2bf(tr[0] * scale); vb.y = f2bf(tr[1] * scale);
  vb.z = f2bf(tr[2] * scale); vb.w = f2bf(tr[3] * scale);
  *(ushort4*)(Vp + ((size_t)((b * 34 + hh + 1) * 34 + (ww + 1))) * 256 + lane * 4) = vb;
  if (lane == 0) NV2[pix] = nt2 * scale * scale;
}

// ---------------------------------------------------------------- BN2 transform + residual + hrelu + [B,C,H,W] store
__global__ __launch_bounds__(256) void k_bntrans_out(const _Float16* __restrict__ Y,
                                                     const float* __restrict__ Y2,
                                                     const float* __restrict__ MU,
                                                     const float* __restrict__ SCAL,
                                                     const float* __restrict__ BIAS,
                                                     const float* __restrict__ WEIGHT,
                                                     const float* __restrict__ PVAR,
                                                     const float* __restrict__ RES,
                                                     float* __restrict__ Out) {
  __shared__ float tile[256 * 33];
  __shared__ float sbv[4];
  int t = threadIdx.x, lane = t & 63, wv = t >> 6;
  float var = pvar_reduce(PVAR, sbv);
  float4 mu4 = ((const float4*)MU)[lane];
  float4 bb4 = ((const float4*)BIAS)[lane];
  float mu2 = SCAL[0], lam_mu = SCAL[1], bias2 = SCAL[2], lam_bias = SCAL[3],
        mubias = SCAL[4];
  float rstd = sqrtf(WEIGHT[0] / fmaxf(var, EPSF));
  float mm[4] = {mu4.x, mu4.y, mu4.z, mu4.w};
  float bs[4] = {bb4.x, bb4.y, bb4.z, bb4.w};
  int pix0 = blockIdx.x * 32;
  for (int it = 0; it < 8; ++it) {
    int p = it * 4 + wv;
    int pix = pix0 + p;
    float x[4], hn2, lamx;
    load_h(Y, Y2, pix, lane, x, hn2, lamx);
    float r[4], nr;
    bn_core<true>(x, mm, bs, mu2, lam_mu, bias2, lam_bias, mubias, rstd, r, nr);
    float h2 = nr * nr;
    float4 rs4 = ((const float4*)RES)[pix * 64 + lane];
    float rr[4] = {rs4.x, rs4.y, rs4.z, rs4.w};
    float y2r = wred(rr[0] * rr[0] + rr[1] * rr[1] + rr[2] * rr[2] + rr[3] * rr[3]);
    float xyr = wred(r[0] * rr[0] + r[1] * rr[1] + r[2] * rr[2] + r[3] * rr[3]);
    float Pm = 1.f + 2.f * xyr + y2r, Qm = 1.f - h2;
    float denmi = frcp(fmaxf(1.f + 2.f * xyr + h2 * y2r, EPSF));
#pragma unroll
    for (int k = 0; k < 4; ++k) r[k] = (Pm * r[k] + Qm * rr[k]) * denmi;
    float nr2 = wred(r[0] * r[0] + r[1] * r[1] + r[2] * r[2] + r[3] * r[3]);
    nr = sqrtf(fmaxf(nr2, EPSF));
    float tf = atanh_fast(fminf(nr, CLIP1)) * frcp(nr);
    float tr[4];
#pragma unroll
    for (int k = 0; k < 4; ++k) tr[k] = fmaxf(tf * r[k], 0.f);
    float nt2 = wred(tr[0] * tr[0] + tr[1] * tr[1] + tr[2] * tr[2] + tr[3] * tr[3]);
    float nt = sqrtf(fmaxf(nt2, EPSF));
    float une = tanh_fast(nt);
    float ef = une * frcp(nt);
    if (une > MAXNRM) ef *= MAXNRM / une;
#pragma unroll
    for (int k = 0; k < 4; ++k) tile[(lane * 4 + k) * 33 + p] = ef * tr[k];
  }
  __syncthreads();
  int b = blockIdx.x >> 5, h = blockIdx.x & 31;
  for (int c0 = 0; c0 < 256; c0 += 8) {
    int c = c0 + (t >> 5), w = t & 31;
    Out[((b * 256 + c) * 32 + h) * 32 + w] = tile[c * 33 + w];
  }
}

// ---------------------------------------------------------------- launch
extern "C" void kernel_launch(void* const* d_in, const int* in_sizes, int n_in,
                              void* d_out, int out_size, void* d_ws, size_t ws_size,
                              hipStream_t stream) {
  (void)in_sizes; (void)n_in; (void)out_size; (void)ws_size;
  const float* x  = (const float*)d_in[0];
  const float* z1 = (const float*)d_in[1];
  const float* z2 = (const float*)d_in[2];
  const float* w1 = (const float*)d_in[3];
  const float* b1 = (const float*)d_in[4];
  const float* w2 = (const float*)d_in[5];
  const float* b2 = (const float*)d_in[6];
  float* out = (float*)d_out;
  float* ws = (float*)d_ws;

  float* zn2   = ws;            // 512
  float* zn    = ws + 512;      // 512
  float* izn   = ws + 1024;     // 512
  float* mu    = ws + 1536;     // 256
  float* scal  = ws + 1792;     // 8
  float* pden  = ws + 1856;     // 512
  float* pvar  = ws + 2368;     // 512
  float* pnum  = ws + 2880;     // 256*512
  float* lf    = ws + 133952;   // 16384
  float* nv2   = ws + 150336;   // 16384
  float* y2    = ws + 166720;   // 16384
  float* xl    = ws + 183104;   // 16 MB
  _Float16* Y  = (_Float16*)(xl + 4194304);  // 16384*256 fp16 = 8 MB
  ushort* Vp   = (ushort*)(Y + 4194304);     // 9.47 MB
  ushort* ZF   = Vp + 4734976;               // 2 x 589824 bf16

  double lb = (lgamma(1152.0) - lgamma(1152.5)) - (lgamma(128.0) - lgamma(128.5));
  float scale = (float)exp(lb);

  hipMemsetAsync(ws, 0, 512 * sizeof(float), stream);   // zn2
  hipMemsetAsync(Vp, 0, (size_t)4734976 * 2, stream);   // zero padding borders
  k_zpack<<<dim3(72, 2), 256, 0, stream>>>(z1, z2, ZF, zn2);

  // ---- conv1
  k_pre1<<<512, 256, 0, stream>>>(x, xl, Vp, nv2, scale);
  k_boxsum<<<64, 256, 0, stream>>>(nv2, zn2, lf, y2, zn, izn);
  k_gemm_mfma<<<512, 256, 0, stream>>>(Vp, ZF, zn, izn, lf, Y, y2);
  k_bnsum<<<512, 256, 0, stream>>>(Y, y2, pnum, pden);
  k_bnmid<<<1, 256, 0, stream>>>(pnum, pden, b1, mu, scal);
  k_bnvar<<<512, 256, 0, stream>>>(Y, y2, mu, scal, pvar);
  k_bntrans_pre<<<4096, 256, 0, stream>>>(Y, y2, mu, scal, b1, w1, pvar, Vp, nv2, scale);

  // ---- conv2
  k_boxsum<<<64, 256, 0, stream>>>(nv2, zn2, lf, y2, zn, izn);
  k_gemm_mfma<<<512, 256, 0, stream>>>(Vp, ZF + 589824, zn + 256, izn + 256, lf, Y, y2);
  k_bnsum<<<512, 256, 0, stream>>>(Y, y2, pnum, pden);
  k_bnmid<<<1, 256, 0, stream>>>(pnum, pden, b2, mu, scal);
  k_bnvar<<<512, 256, 0, stream>>>(Y, y2, mu, scal, pvar);
  k_bntrans_out<<<512, 256, 0, stream>>>(Y, y2, mu, scal, b2, w2, pvar, xl, out);
}